// Round 1
// baseline (1395.840 us; speedup 1.0000x reference)
//
#include <hip/hip_runtime.h>
#include <hip/hip_bf16.h>

// Problem: C[b][o] = sum_i x[b][i] * ternary(w[o][i]);  ternary = sign(w)*(|w|>=0.33)
// M=8192 (batch), K=4096 (in), N=16384 (out). Output f32 row-major [M][N].
#define M_DIM 8192
#define K_DIM 4096
#define N_DIM 16384
#define BM 128
#define BN 128
#define BK 64

typedef __attribute__((ext_vector_type(8))) short bf16x8;
typedef __attribute__((ext_vector_type(4))) float f32x4;

typedef __attribute__((address_space(1))) const void glb_cv;
typedef __attribute__((address_space(3))) void lds_v;

// ---------- prepass 1: x f32 -> bf16 (round-to-nearest-even), 8 elems/thread ----------
__global__ void cvt_x_bf16(const float* __restrict__ x, ushort* __restrict__ xb) {
    long i = (long)blockIdx.x * blockDim.x + threadIdx.x;   // 8 floats per thread
    const float4* src = reinterpret_cast<const float4*>(x) + i * 2;
    float4 a = src[0], b = src[1];
    float v[8] = {a.x, a.y, a.z, a.w, b.x, b.y, b.z, b.w};
    unsigned r[8];
#pragma unroll
    for (int j = 0; j < 8; ++j) {
        unsigned u = __float_as_uint(v[j]);
        r[j] = (u + 0x7fffu + ((u >> 16) & 1u)) >> 16;      // RNE to bf16
    }
    uint4 o;
    o.x = r[0] | (r[1] << 16);
    o.y = r[2] | (r[3] << 16);
    o.z = r[4] | (r[5] << 16);
    o.w = r[6] | (r[7] << 16);
    reinterpret_cast<uint4*>(xb)[i] = o;
}

// ---------- prepass 2: w f32 -> ternary bf16 {-1,0,+1}, 8 elems/thread ----------
__global__ void ternarize_w(const float* __restrict__ w, ushort* __restrict__ wb) {
    long i = (long)blockIdx.x * blockDim.x + threadIdx.x;
    const float4* src = reinterpret_cast<const float4*>(w) + i * 2;
    float4 a = src[0], b = src[1];
    float v[8] = {a.x, a.y, a.z, a.w, b.x, b.y, b.z, b.w};
    unsigned r[8];
#pragma unroll
    for (int j = 0; j < 8; ++j) {
        unsigned u = __float_as_uint(v[j]);
        // bf16 +1.0 = 0x3F80, -1.0 = 0xBF80, 0 = 0x0000
        r[j] = (fabsf(v[j]) >= 0.33f) ? (0x3F80u | ((u >> 16) & 0x8000u)) : 0u;
    }
    uint4 o;
    o.x = r[0] | (r[1] << 16);
    o.y = r[2] | (r[3] << 16);
    o.z = r[4] | (r[5] << 16);
    o.w = r[6] | (r[7] << 16);
    reinterpret_cast<uint4*>(wb)[i] = o;
}

// ---------- GEMM: C = A(bf16, MxK) @ B(bf16, NxK)^T, both K-major ----------
// m97 structure: 128x128 tile, BK=64, 4 waves, 16x16x32 MFMA, 4x4 frags/wave.
// LDS staged via global_load_lds width=16 (linear dest) with pre-swizzled global
// source; ds_read applies the same XOR involution (slot ^= row&7) -> no 16-way
// bank conflict on the 128B-stride rows.
__global__ __launch_bounds__(256, 2) void gemm_bt(const ushort* __restrict__ A,
                                                  const ushort* __restrict__ Bm,
                                                  float* __restrict__ C) {
    __shared__ ushort As[BM * BK];   // 16 KB
    __shared__ ushort Bs[BN * BK];   // 16 KB

    // XCD-aware swizzle: grid = 8192, 8192 % 8 == 0 -> simple form is bijective.
    unsigned bid = blockIdx.x;
    unsigned wg  = (bid & 7u) * (gridDim.x >> 3) + (bid >> 3);
    unsigned tm0 = (wg >> 7) * BM;     // N_DIM/BN = 128 tiles per row-panel
    unsigned tn0 = (wg & 127u) * BN;

    const int tid  = threadIdx.x;
    const int lane = tid & 63;
    const int wave = tid >> 6;
    const int wm   = wave >> 1;        // wave sub-tile 64x64
    const int wn   = wave & 1;
    const int lrow = lane & 15;
    const int kgrp = lane >> 4;

    f32x4 acc[4][4] = {};

    for (int k0 = 0; k0 < K_DIM; k0 += BK) {
        // ---- stage A,B tiles: 1024 slots of 16B each, 4 per thread ----
#pragma unroll
        for (int i = 0; i < 4; ++i) {
            int s   = tid + i * 256;
            int row = s >> 3;                       // 8 slots per 128B row
            int ls  = (s & 7) ^ (row & 7);          // inverse-swizzled source slot
            const ushort* ga = A  + (size_t)(tm0 + row) * K_DIM + k0 + ls * 8;
            const ushort* gb = Bm + (size_t)(tn0 + row) * K_DIM + k0 + ls * 8;
            __builtin_amdgcn_global_load_lds((glb_cv*)ga, (lds_v*)&As[s * 8], 16, 0, 0);
            __builtin_amdgcn_global_load_lds((glb_cv*)gb, (lds_v*)&Bs[s * 8], 16, 0, 0);
        }
        __syncthreads();

        // ---- compute: 2 k-chunks of 32, 16 MFMA each ----
#pragma unroll
        for (int c = 0; c < 2; ++c) {
            bf16x8 af[4], bfr[4];
            const unsigned kb = c * 64 + kgrp * 16; // logical byte offset in row
#pragma unroll
            for (int m = 0; m < 4; ++m) {
                int r = wm * 64 + m * 16 + lrow;
                unsigned off = (unsigned)r * 128u + (kb ^ ((unsigned)(r & 7) << 4));
                af[m] = *reinterpret_cast<const bf16x8*>(
                    reinterpret_cast<const char*>(As) + off);
            }
#pragma unroll
            for (int n = 0; n < 4; ++n) {
                int r = wn * 64 + n * 16 + lrow;
                unsigned off = (unsigned)r * 128u + (kb ^ ((unsigned)(r & 7) << 4));
                bfr[n] = *reinterpret_cast<const bf16x8*>(
                    reinterpret_cast<const char*>(Bs) + off);
            }
#pragma unroll
            for (int m = 0; m < 4; ++m)
#pragma unroll
                for (int n = 0; n < 4; ++n)
                    acc[m][n] = __builtin_amdgcn_mfma_f32_16x16x32_bf16(
                        af[m], bfr[n], acc[m][n], 0, 0, 0);
        }
        __syncthreads();
    }

    // ---- epilogue: C/D layout col = lane&15, row = (lane>>4)*4 + reg (m89) ----
#pragma unroll
    for (int m = 0; m < 4; ++m) {
#pragma unroll
        for (int n = 0; n < 4; ++n) {
#pragma unroll
            for (int r = 0; r < 4; ++r) {
                int row = tm0 + wm * 64 + m * 16 + kgrp * 4 + r;
                int col = tn0 + wn * 64 + n * 16 + lrow;
                C[(size_t)row * N_DIM + col] = acc[m][n][r];
            }
        }
    }
}

extern "C" void kernel_launch(void* const* d_in, const int* in_sizes, int n_in,
                              void* d_out, int out_size, void* d_ws, size_t ws_size,
                              hipStream_t stream) {
    const float* x = (const float*)d_in[0];
    const float* w = (const float*)d_in[1];
    // d_in[2] (mask) is unused: forward value is exactly the ternarized weight.
    float* out = (float*)d_out;

    ushort* xb = (ushort*)d_ws;                       // 8192*4096 bf16 = 64 MB
    ushort* wb = xb + (size_t)M_DIM * K_DIM;          // 16384*4096 bf16 = 128 MB

    {   // x -> bf16 : 33.5M elems, 8/thread
        int n8 = M_DIM * K_DIM / 8;
        cvt_x_bf16<<<n8 / 256, 256, 0, stream>>>(x, xb);
    }
    {   // w -> ternary bf16 : 67.1M elems, 8/thread
        int n8 = N_DIM * K_DIM / 8;
        ternarize_w<<<n8 / 256, 256, 0, stream>>>(w, wb);
    }
    {   // GEMM
        dim3 grid((M_DIM / BM) * (N_DIM / BN));       // 64*128 = 8192 blocks
        gemm_bt<<<grid, dim3(256), 0, stream>>>(xb, wb, out);
    }
}

// Round 2
// 1188.889 us; speedup vs baseline: 1.1741x; 1.1741x over previous
//
#include <hip/hip_runtime.h>
#include <hip/hip_bf16.h>

// C[b][o] = sum_i x[b][i] * ternary(w[o][i]);  ternary = sign(w)*(|w|>=0.33)
// M=8192, K=4096, N=16384. Output f32 row-major [M][N].
#define M_DIM 8192
#define K_DIM 4096
#define N_DIM 16384
#define BK 64
#define NT (K_DIM / BK)   // 64 k-tiles

typedef __attribute__((ext_vector_type(8))) short bf16x8;
typedef __attribute__((ext_vector_type(4))) float f32x4;
typedef __attribute__((address_space(1))) const void glb_cv;
typedef __attribute__((address_space(3))) void lds_v;

// ---------- prepass 1: x f32 -> bf16 (RNE), 8 elems/thread ----------
__global__ void cvt_x_bf16(const float* __restrict__ x, ushort* __restrict__ xb) {
    long i = (long)blockIdx.x * blockDim.x + threadIdx.x;
    const float4* src = reinterpret_cast<const float4*>(x) + i * 2;
    float4 a = src[0], b = src[1];
    float v[8] = {a.x, a.y, a.z, a.w, b.x, b.y, b.z, b.w};
    unsigned r[8];
#pragma unroll
    for (int j = 0; j < 8; ++j) {
        unsigned u = __float_as_uint(v[j]);
        r[j] = (u + 0x7fffu + ((u >> 16) & 1u)) >> 16;
    }
    uint4 o;
    o.x = r[0] | (r[1] << 16);
    o.y = r[2] | (r[3] << 16);
    o.z = r[4] | (r[5] << 16);
    o.w = r[6] | (r[7] << 16);
    reinterpret_cast<uint4*>(xb)[i] = o;
}

// ---------- prepass 2: w f32 -> ternary bf16 {-1,0,+1}, 8 elems/thread ----------
__global__ void ternarize_w(const float* __restrict__ w, ushort* __restrict__ wb) {
    long i = (long)blockIdx.x * blockDim.x + threadIdx.x;
    const float4* src = reinterpret_cast<const float4*>(w) + i * 2;
    float4 a = src[0], b = src[1];
    float v[8] = {a.x, a.y, a.z, a.w, b.x, b.y, b.z, b.w};
    unsigned r[8];
#pragma unroll
    for (int j = 0; j < 8; ++j) {
        unsigned u = __float_as_uint(v[j]);
        r[j] = (fabsf(v[j]) >= 0.33f) ? (0x3F80u | ((u >> 16) & 0x8000u)) : 0u;
    }
    uint4 o;
    o.x = r[0] | (r[1] << 16);
    o.y = r[2] | (r[3] << 16);
    o.z = r[4] | (r[5] << 16);
    o.w = r[6] | (r[7] << 16);
    reinterpret_cast<uint4*>(wb)[i] = o;
}

// ---------- GEMM: 256x256 tile, BK=64, 8 waves, 8-phase counted-vmcnt pipeline ----------
// LDS (ushort units): [buf2:32768][op2:16384][chunk2:8192][row256:32][slot4:8]
//   chunk c holds k-elems [32c,32c+32) of the K-tile; row stride 64B; slot = 16B.
// Swizzle: phys_slot = logical_slot ^ ((row>>1)&3)  (applied on read AND on the
//   pre-swizzled global source; LDS dest of global_load_lds stays linear).
// Staging unit = (op, chunk, row-half) = 8KB = 512 thr x 16B = 1 gload round.
// Schedule per K-tile kt (buf P=kt&1, Q=P^1), phases p=0..3, c=p>>1, mu=p&1:
//   p0: stage A-chunk1(kt+1)->Q   p1: stage B-chunk1(kt+1)->Q
//   p2: stage A-chunk0(kt+2)->P   p3: stage B-chunk0(kt+2)->P
//   (chunk0 of buf P retires at end of p1 -> p2/p3 overwrite is barrier-safe)
// One s_waitcnt vmcnt(4) per K-tile (end of p3): drains tile kt+1 fully,
// leaves kt+2's chunk0 (4 loads) in flight. Tail (kt+2>=NT): vmcnt(0).
__global__ __launch_bounds__(512, 2) void gemm_bt(const ushort* __restrict__ A,
                                                  const ushort* __restrict__ Bm,
                                                  float* __restrict__ C) {
    __shared__ ushort sh[65536];   // 128 KB

    unsigned bid = blockIdx.x;
    unsigned wg  = (bid & 7u) * 256u + (bid >> 3);   // 2048 % 8 == 0 -> bijective
    const unsigned tm0 = (wg >> 6) * 256u;           // 32 row-tiles
    const unsigned tn0 = (wg & 63u) * 256u;          // 64 col-tiles

    const int tid  = threadIdx.x;
    const int lane = tid & 63;
    const int wid  = tid >> 6;
    const int wm   = wid >> 2;        // 0..1 -> rows wm*128
    const int wn   = wid & 3;         // 0..3 -> cols wn*64
    const int lrow = lane & 15;
    const int kg   = lane >> 4;

    // staging decomposition (per thread): row in half, phys slot, logical slot
    const int srow = tid >> 2;                  // 0..127
    const int sg   = (tid & 3) ^ ((tid >> 3) & 3);
    const int sdst = tid * 8;                   // ushort offset within unit

    f32x4 acc[8][4] = {};

#define STAGE_A(kt_, c_, h_, P_) do {                                                       \
        const ushort* _s = A + (size_t)(tm0 + (h_)*128 + srow) * K_DIM                      \
                             + (kt_)*BK + (c_)*32 + sg*8;                                   \
        __builtin_amdgcn_global_load_lds((glb_cv*)_s,                                       \
            (lds_v*)&sh[(P_)*32768 + (c_)*8192 + (h_)*4096 + sdst], 16, 0, 0);              \
    } while (0)
#define STAGE_B(kt_, c_, h_, P_) do {                                                       \
        const ushort* _s = Bm + (size_t)(tn0 + (h_)*128 + srow) * K_DIM                     \
                              + (kt_)*BK + (c_)*32 + sg*8;                                  \
        __builtin_amdgcn_global_load_lds((glb_cv*)_s,                                       \
            (lds_v*)&sh[(P_)*32768 + 16384 + (c_)*8192 + (h_)*4096 + sdst], 16, 0, 0);      \
    } while (0)

    // ---- prologue: tile0 all 8 units -> buf0; tile1 chunk0 4 units -> buf1 ----
    STAGE_A(0, 0, 0, 0); STAGE_A(0, 0, 1, 0);
    STAGE_B(0, 0, 0, 0); STAGE_B(0, 0, 1, 0);
    STAGE_A(0, 1, 0, 0); STAGE_A(0, 1, 1, 0);
    STAGE_B(0, 1, 0, 0); STAGE_B(0, 1, 1, 0);
    STAGE_A(1, 0, 0, 1); STAGE_A(1, 0, 1, 1);
    STAGE_B(1, 0, 0, 1); STAGE_B(1, 0, 1, 1);
    asm volatile("s_waitcnt vmcnt(4)" ::: "memory");
    __builtin_amdgcn_s_barrier();
    __builtin_amdgcn_sched_barrier(0);

    for (int kt = 0; kt < NT; ++kt) {
        const int P = kt & 1;
        const int Q = P ^ 1;
        const unsigned ab = P * 32768u;
        const unsigned bb = ab + 16384u;
        bf16x8 bq[4];
#pragma unroll
        for (int p = 0; p < 4; ++p) {
            const int c  = p >> 1;
            const int mu = p & 1;
            bf16x8 aq[4];
            if (mu == 0) {
#pragma unroll
                for (int n = 0; n < 4; ++n) {
                    int r = wn * 64 + n * 16 + lrow;
                    bq[n] = *(const bf16x8*)&sh[bb + c * 8192 + r * 32 + 8 * (kg ^ ((r >> 1) & 3))];
                }
            }
#pragma unroll
            for (int i = 0; i < 4; ++i) {
                int r = wm * 128 + (mu * 4 + i) * 16 + lrow;
                aq[i] = *(const bf16x8*)&sh[ab + c * 8192 + r * 32 + 8 * (kg ^ ((r >> 1) & 3))];
            }
            if (p == 0 && kt + 1 < NT) { STAGE_A(kt + 1, 1, 0, Q); STAGE_A(kt + 1, 1, 1, Q); }
            if (p == 1 && kt + 1 < NT) { STAGE_B(kt + 1, 1, 0, Q); STAGE_B(kt + 1, 1, 1, Q); }
            if (p == 2 && kt + 2 < NT) { STAGE_A(kt + 2, 0, 0, P); STAGE_A(kt + 2, 0, 1, P); }
            if (p == 3 && kt + 2 < NT) { STAGE_B(kt + 2, 0, 0, P); STAGE_B(kt + 2, 0, 1, P); }

            __builtin_amdgcn_s_barrier();
            asm volatile("s_waitcnt lgkmcnt(0)" ::: "memory");
            __builtin_amdgcn_sched_barrier(0);
            __builtin_amdgcn_s_setprio(1);
#pragma unroll
            for (int i = 0; i < 4; ++i)
#pragma unroll
                for (int n = 0; n < 4; ++n)
                    acc[mu * 4 + i][n] = __builtin_amdgcn_mfma_f32_16x16x32_bf16(
                        aq[i], bq[n], acc[mu * 4 + i][n], 0, 0, 0);
            __builtin_amdgcn_s_setprio(0);
            if (p == 3) {
                if (kt + 2 < NT) asm volatile("s_waitcnt vmcnt(4)" ::: "memory");
                else             asm volatile("s_waitcnt vmcnt(0)" ::: "memory");
            }
            __builtin_amdgcn_s_barrier();
            __builtin_amdgcn_sched_barrier(0);
        }
    }

    // ---- epilogue: C/D layout col = lane&15, row = (lane>>4)*4 + reg ----
#pragma unroll
    for (int m = 0; m < 8; ++m)
#pragma unroll
        for (int n = 0; n < 4; ++n)
#pragma unroll
            for (int r = 0; r < 4; ++r) {
                int row = tm0 + wm * 128 + m * 16 + kg * 4 + r;
                int col = tn0 + wn * 64 + n * 16 + lrow;
                C[(size_t)row * N_DIM + col] = acc[m][n][r];
            }
#undef STAGE_A
#undef STAGE_B
}

extern "C" void kernel_launch(void* const* d_in, const int* in_sizes, int n_in,
                              void* d_out, int out_size, void* d_ws, size_t ws_size,
                              hipStream_t stream) {
    const float* x = (const float*)d_in[0];
    const float* w = (const float*)d_in[1];
    // d_in[2] (mask) unused: forward value is exactly the ternarized weight.
    float* out = (float*)d_out;

    ushort* xb = (ushort*)d_ws;                       // 64 MB
    ushort* wb = xb + (size_t)M_DIM * K_DIM;          // 128 MB

    {
        int n8 = M_DIM * K_DIM / 8;
        cvt_x_bf16<<<n8 / 256, 256, 0, stream>>>(x, xb);
    }
    {
        int n8 = N_DIM * K_DIM / 8;
        ternarize_w<<<n8 / 256, 256, 0, stream>>>(w, wb);
    }
    {
        dim3 grid((M_DIM / 256) * (N_DIM / 256));     // 32*64 = 2048 blocks
        gemm_bt<<<grid, dim3(512), 0, stream>>>(xb, wb, out);
    }
}

// Round 3
// 1181.745 us; speedup vs baseline: 1.1812x; 1.0060x over previous
//
#include <hip/hip_runtime.h>
#include <hip/hip_bf16.h>

// C[b][o] = sum_i x[b][i] * ternary(w[o][i]);  ternary = sign(w)*(|w|>=0.33)
// M=8192, K=4096, N=16384. Output f32 row-major [M][N].
#define M_DIM 8192
#define K_DIM 4096
#define N_DIM 16384
#define BK 64
#define NT (K_DIM / BK)   // 64 k-tiles

typedef __attribute__((ext_vector_type(8))) short bf16x8;
typedef __attribute__((ext_vector_type(4))) float f32x4;
typedef __attribute__((address_space(1))) const void glb_cv;
typedef __attribute__((address_space(3))) void lds_v;

// ---------- prepass 1: x f32 -> bf16 (RNE), 8 elems/thread ----------
__global__ void cvt_x_bf16(const float* __restrict__ x, ushort* __restrict__ xb) {
    long i = (long)blockIdx.x * blockDim.x + threadIdx.x;
    const float4* src = reinterpret_cast<const float4*>(x) + i * 2;
    float4 a = src[0], b = src[1];
    float v[8] = {a.x, a.y, a.z, a.w, b.x, b.y, b.z, b.w};
    unsigned r[8];
#pragma unroll
    for (int j = 0; j < 8; ++j) {
        unsigned u = __float_as_uint(v[j]);
        r[j] = (u + 0x7fffu + ((u >> 16) & 1u)) >> 16;
    }
    uint4 o;
    o.x = r[0] | (r[1] << 16);
    o.y = r[2] | (r[3] << 16);
    o.z = r[4] | (r[5] << 16);
    o.w = r[6] | (r[7] << 16);
    reinterpret_cast<uint4*>(xb)[i] = o;
}

// ---------- prepass 2: w f32 -> ternary bf16 {-1,0,+1}, 8 elems/thread ----------
__global__ void ternarize_w(const float* __restrict__ w, ushort* __restrict__ wb) {
    long i = (long)blockIdx.x * blockDim.x + threadIdx.x;
    const float4* src = reinterpret_cast<const float4*>(w) + i * 2;
    float4 a = src[0], b = src[1];
    float v[8] = {a.x, a.y, a.z, a.w, b.x, b.y, b.z, b.w};
    unsigned r[8];
#pragma unroll
    for (int j = 0; j < 8; ++j) {
        unsigned u = __float_as_uint(v[j]);
        r[j] = (fabsf(v[j]) >= 0.33f) ? (0x3F80u | ((u >> 16) & 0x8000u)) : 0u;
    }
    uint4 o;
    o.x = r[0] | (r[1] << 16);
    o.y = r[2] | (r[3] << 16);
    o.z = r[4] | (r[5] << 16);
    o.w = r[6] | (r[7] << 16);
    reinterpret_cast<uint4*>(wb)[i] = o;
}

// ---------- GEMM: 256x256 tile, BK=64, 8 waves, 4-phase/tile deep-pipelined ----------
// LDS (ushort units): [buf2:32768][op2:16384][chunk2:8192][row256:32][slot4:8]
// Swizzle: phys_slot = logical_slot ^ ((row>>1)&3); LDS dest of global_load_lds
// stays linear, global source is inverse-swizzled, ds_read applies the XOR.
//
// Deep schedule (steady state), tile kt, buf P=kt&1, Q=P^1:
//   p0 (c0,mu0): reads chunk0 P; STAGE chunk1(kt+1)->Q  (4 loads)
//   p1 (c0,mu1): reads chunk0 P; drain vmcnt(8)  [retires chunk1(kt), issued kt-1 p0]
//   p2 (c1,mu0): reads chunk1 P; STAGE chunk0(kt+2)->P  (4 loads)
//   p3 (c1,mu1): reads chunk1 P; drain vmcnt(8)  [retires chunk0(kt+1), issued kt-1 p2]
// Issue->drain distance = 5 phases (~1800 cyc) >> HBM latency; 8-12 loads
// (64-96KB) in flight, never drained below 8 in the main loop.
// Liveness: Q.chunk1 dead after kt-1 p3 barrier (overwrite at kt p0 ok);
//           P.chunk0 dead after kt p1 barrier (overwrite at kt p2 ok).
// Tail: p1 -> vmcnt(0) when kt+1>=NT; p3 -> vmcnt(4) when only chunk1(kt+1)
//       remains, vmcnt(0) when nothing staged.
__global__ __launch_bounds__(512, 2) void gemm_bt(const ushort* __restrict__ A,
                                                  const ushort* __restrict__ Bm,
                                                  float* __restrict__ C) {
    __shared__ ushort sh[65536];   // 128 KB

    unsigned bid = blockIdx.x;
    unsigned wg  = (bid & 7u) * 256u + (bid >> 3);   // 2048 % 8 == 0 -> bijective
    const unsigned tm0 = (wg >> 6) * 256u;           // 32 row-tiles
    const unsigned tn0 = (wg & 63u) * 256u;          // 64 col-tiles

    const int tid  = threadIdx.x;
    const int lane = tid & 63;
    const int wid  = tid >> 6;
    const int wm   = wid >> 2;        // 0..1 -> rows wm*128
    const int wn   = wid & 3;         // 0..3 -> cols wn*64
    const int lrow = lane & 15;
    const int kg   = lane >> 4;

    // staging decomposition (per thread): row-in-half, inverse-swizzled slot
    const int srow = tid >> 2;                  // 0..127
    const int sg   = (tid & 3) ^ ((tid >> 3) & 3);
    const int sdst = tid * 8;                   // ushort offset within 8KB unit

    f32x4 acc[8][4] = {};

#define STAGE_A(kt_, c_, h_, P_) do {                                                       \
        const ushort* _s = A + (size_t)(tm0 + (h_)*128 + srow) * K_DIM                      \
                             + (kt_)*BK + (c_)*32 + sg*8;                                   \
        __builtin_amdgcn_global_load_lds((glb_cv*)_s,                                       \
            (lds_v*)&sh[(P_)*32768 + (c_)*8192 + (h_)*4096 + sdst], 16, 0, 0);              \
    } while (0)
#define STAGE_B(kt_, c_, h_, P_) do {                                                       \
        const ushort* _s = Bm + (size_t)(tn0 + (h_)*128 + srow) * K_DIM                     \
                              + (kt_)*BK + (c_)*32 + sg*8;                                  \
        __builtin_amdgcn_global_load_lds((glb_cv*)_s,                                       \
            (lds_v*)&sh[(P_)*32768 + 16384 + (c_)*8192 + (h_)*4096 + sdst], 16, 0, 0);      \
    } while (0)

    // ---- prologue: chunk0(0)+chunk1(0) -> buf0, chunk0(1) -> buf1 ----
    STAGE_A(0, 0, 0, 0); STAGE_A(0, 0, 1, 0);
    STAGE_B(0, 0, 0, 0); STAGE_B(0, 0, 1, 0);
    STAGE_A(0, 1, 0, 0); STAGE_A(0, 1, 1, 0);
    STAGE_B(0, 1, 0, 0); STAGE_B(0, 1, 1, 0);
    STAGE_A(1, 0, 0, 1); STAGE_A(1, 0, 1, 1);
    STAGE_B(1, 0, 0, 1); STAGE_B(1, 0, 1, 1);
    asm volatile("s_waitcnt vmcnt(8)" ::: "memory");   // chunk0(0) ready
    __builtin_amdgcn_s_barrier();
    __builtin_amdgcn_sched_barrier(0);

    for (int kt = 0; kt < NT; ++kt) {
        const int P = kt & 1;
        const int Q = P ^ 1;
        const unsigned ab = P * 32768u;
        const unsigned bb = ab + 16384u;
        bf16x8 bq[4];
#pragma unroll
        for (int p = 0; p < 4; ++p) {
            const int c  = p >> 1;
            const int mu = p & 1;
            bf16x8 aq[4];
            if (mu == 0) {
#pragma unroll
                for (int n = 0; n < 4; ++n) {
                    int r = wn * 64 + n * 16 + lrow;
                    bq[n] = *(const bf16x8*)&sh[bb + c * 8192 + r * 32 + 8 * (kg ^ ((r >> 1) & 3))];
                }
            }
#pragma unroll
            for (int i = 0; i < 4; ++i) {
                int r = wm * 128 + (mu * 4 + i) * 16 + lrow;
                aq[i] = *(const bf16x8*)&sh[ab + c * 8192 + r * 32 + 8 * (kg ^ ((r >> 1) & 3))];
            }
            if (p == 0 && kt + 1 < NT) {
                STAGE_A(kt + 1, 1, 0, Q); STAGE_A(kt + 1, 1, 1, Q);
                STAGE_B(kt + 1, 1, 0, Q); STAGE_B(kt + 1, 1, 1, Q);
            }
            if (p == 2 && kt + 2 < NT) {
                STAGE_A(kt + 2, 0, 0, P); STAGE_A(kt + 2, 0, 1, P);
                STAGE_B(kt + 2, 0, 0, P); STAGE_B(kt + 2, 0, 1, P);
            }

            __builtin_amdgcn_s_barrier();
            asm volatile("s_waitcnt lgkmcnt(0)" ::: "memory");
            __builtin_amdgcn_sched_barrier(0);
            __builtin_amdgcn_s_setprio(1);
#pragma unroll
            for (int i = 0; i < 4; ++i)
#pragma unroll
                for (int n = 0; n < 4; ++n)
                    acc[mu * 4 + i][n] = __builtin_amdgcn_mfma_f32_16x16x32_bf16(
                        aq[i], bq[n], acc[mu * 4 + i][n], 0, 0, 0);
            __builtin_amdgcn_s_setprio(0);
            if (p == 1) {   // retire chunk1(kt) before p2 reads it
                if (kt + 1 < NT) asm volatile("s_waitcnt vmcnt(8)" ::: "memory");
                else             asm volatile("s_waitcnt vmcnt(0)" ::: "memory");
            }
            if (p == 3) {   // retire chunk0(kt+1) before next tile's p0 reads it
                if (kt + 2 < NT)      asm volatile("s_waitcnt vmcnt(8)" ::: "memory");
                else if (kt + 1 < NT) asm volatile("s_waitcnt vmcnt(4)" ::: "memory");
                else                  asm volatile("s_waitcnt vmcnt(0)" ::: "memory");
            }
            __builtin_amdgcn_s_barrier();
            __builtin_amdgcn_sched_barrier(0);
        }
    }

    // ---- epilogue: C/D layout col = lane&15, row = (lane>>4)*4 + reg ----
#pragma unroll
    for (int m = 0; m < 8; ++m)
#pragma unroll
        for (int n = 0; n < 4; ++n)
#pragma unroll
            for (int r = 0; r < 4; ++r) {
                int row = tm0 + wm * 128 + m * 16 + kg * 4 + r;
                int col = tn0 + wn * 64 + n * 16 + lrow;
                C[(size_t)row * N_DIM + col] = acc[m][n][r];
            }
#undef STAGE_A
#undef STAGE_B
}

extern "C" void kernel_launch(void* const* d_in, const int* in_sizes, int n_in,
                              void* d_out, int out_size, void* d_ws, size_t ws_size,
                              hipStream_t stream) {
    const float* x = (const float*)d_in[0];
    const float* w = (const float*)d_in[1];
    // d_in[2] (mask) unused: forward value is exactly the ternarized weight.
    float* out = (float*)d_out;

    ushort* xb = (ushort*)d_ws;                       // 64 MB
    ushort* wb = xb + (size_t)M_DIM * K_DIM;          // 128 MB

    {
        int n8 = M_DIM * K_DIM / 8;
        cvt_x_bf16<<<n8 / 256, 256, 0, stream>>>(x, xb);
    }
    {
        int n8 = N_DIM * K_DIM / 8;
        ternarize_w<<<n8 / 256, 256, 0, stream>>>(w, wb);
    }
    {
        dim3 grid((M_DIM / 256) * (N_DIM / 256));     // 32*64 = 2048 blocks
        gemm_bt<<<grid, dim3(512), 0, stream>>>(xb, wb, out);
    }
}

// Round 4
// 1116.556 us; speedup vs baseline: 1.2501x; 1.0584x over previous
//
#include <hip/hip_runtime.h>
#include <hip/hip_bf16.h>

// C[b][o] = sum_i x[b][i] * ternary(w[o][i]);  ternary = sign(w)*(|w|>=0.33)
// M=8192, K=4096, N=16384. Output f32 row-major [M][N].
#define M_DIM 8192
#define K_DIM 4096
#define N_DIM 16384
#define BK 64
#define NT (K_DIM / BK)   // 64 k-tiles

typedef __attribute__((ext_vector_type(8))) short bf16x8;
typedef __attribute__((ext_vector_type(4))) float f32x4;
typedef __attribute__((address_space(1))) const void glb_cv;
typedef __attribute__((address_space(3))) void lds_v;

// ---------- prepass 1: x f32 -> bf16 (RNE), 8 elems/thread ----------
__global__ void cvt_x_bf16(const float* __restrict__ x, ushort* __restrict__ xb) {
    long i = (long)blockIdx.x * blockDim.x + threadIdx.x;
    const float4* src = reinterpret_cast<const float4*>(x) + i * 2;
    float4 a = src[0], b = src[1];
    float v[8] = {a.x, a.y, a.z, a.w, b.x, b.y, b.z, b.w};
    unsigned r[8];
#pragma unroll
    for (int j = 0; j < 8; ++j) {
        unsigned u = __float_as_uint(v[j]);
        r[j] = (u + 0x7fffu + ((u >> 16) & 1u)) >> 16;
    }
    uint4 o;
    o.x = r[0] | (r[1] << 16);
    o.y = r[2] | (r[3] << 16);
    o.z = r[4] | (r[5] << 16);
    o.w = r[6] | (r[7] << 16);
    reinterpret_cast<uint4*>(xb)[i] = o;
}

// ---------- prepass 2: w f32 -> ternary bf16 {-1,0,+1}, 8 elems/thread ----------
__global__ void ternarize_w(const float* __restrict__ w, ushort* __restrict__ wb) {
    long i = (long)blockIdx.x * blockDim.x + threadIdx.x;
    const float4* src = reinterpret_cast<const float4*>(w) + i * 2;
    float4 a = src[0], b = src[1];
    float v[8] = {a.x, a.y, a.z, a.w, b.x, b.y, b.z, b.w};
    unsigned r[8];
#pragma unroll
    for (int j = 0; j < 8; ++j) {
        unsigned u = __float_as_uint(v[j]);
        r[j] = (fabsf(v[j]) >= 0.33f) ? (0x3F80u | ((u >> 16) & 0x8000u)) : 0u;
    }
    uint4 o;
    o.x = r[0] | (r[1] << 16);
    o.y = r[2] | (r[3] << 16);
    o.z = r[4] | (r[5] << 16);
    o.w = r[6] | (r[7] << 16);
    reinterpret_cast<uint4*>(wb)[i] = o;
}

// ---------- GEMM: 256x256 tile, BK=64, 8 waves, 2 half-tile phases per K-tile ----------
// LDS (ushort units): [buf2:32768][op2:16384][chunk2:8192][row256:32][slot4:8]
// Swizzle: phys_slot = logical_slot ^ ((row>>1)&3); LDS dest of global_load_lds
// stays linear, global source is inverse-swizzled, ds_read applies the XOR.
//
// Per half-tile (c = k-chunk): {12 ds_read (aq[8]+bq[4]); 4-unit STAGE;
//   setprio(1); 32 MFMA; setprio(0); counted vmcnt; s_barrier}.
// NO explicit lgkmcnt before the MFMAs: the compiler emits fine-grained
// lgkmcnt(N) per operand, so read-return latency hides under the MFMA stream.
// Staging (4-load units): c0 stages chunk1(kt+1)->Q, c1 stages chunk0(kt+2)->P.
// Drains: c0 vmcnt(8) retires chunk1(kt) (staged kt-1.c0, published by this
// barrier for c1's reads); c1 vmcnt(8) retires chunk0(kt+1) (staged kt-1.c1,
// published for next tile's c0). 8-12 loads (64-96KB) stay in flight.
// Overwrite safety: every STAGE lands in a chunk whose last readers' MFMAs
// completed before the preceding barrier; every read follows the vmcnt+barrier
// that retired/published its staging. asm "memory" clobbers on the vmcnt
// waits pin all LDS/global motion at each publish point.
__global__ __launch_bounds__(512, 2) void gemm_bt(const ushort* __restrict__ A,
                                                  const ushort* __restrict__ Bm,
                                                  float* __restrict__ C) {
    __shared__ ushort sh[65536];   // 128 KB

    unsigned bid = blockIdx.x;
    unsigned wg  = (bid & 7u) * 256u + (bid >> 3);   // 2048 % 8 == 0 -> bijective
    const unsigned tm0 = (wg >> 6) * 256u;           // 32 row-tiles
    const unsigned tn0 = (wg & 63u) * 256u;          // 64 col-tiles

    const int tid  = threadIdx.x;
    const int lane = tid & 63;
    const int wid  = tid >> 6;
    const int wm   = wid >> 2;        // 0..1 -> rows wm*128
    const int wn   = wid & 3;         // 0..3 -> cols wn*64
    const int lrow = lane & 15;
    const int kg   = lane >> 4;

    // staging decomposition (per thread): row-in-half, inverse-swizzled slot
    const int srow = tid >> 2;                  // 0..127
    const int sg   = (tid & 3) ^ ((tid >> 3) & 3);
    const int sdst = tid * 8;                   // ushort offset within 8KB unit

    f32x4 acc[8][4] = {};

#define STAGE_A(kt_, c_, h_, P_) do {                                                       \
        const ushort* _s = A + (size_t)(tm0 + (h_)*128 + srow) * K_DIM                      \
                             + (kt_)*BK + (c_)*32 + sg*8;                                   \
        __builtin_amdgcn_global_load_lds((glb_cv*)_s,                                       \
            (lds_v*)&sh[(P_)*32768 + (c_)*8192 + (h_)*4096 + sdst], 16, 0, 0);              \
    } while (0)
#define STAGE_B(kt_, c_, h_, P_) do {                                                       \
        const ushort* _s = Bm + (size_t)(tn0 + (h_)*128 + srow) * K_DIM                     \
                              + (kt_)*BK + (c_)*32 + sg*8;                                  \
        __builtin_amdgcn_global_load_lds((glb_cv*)_s,                                       \
            (lds_v*)&sh[(P_)*32768 + 16384 + (c_)*8192 + (h_)*4096 + sdst], 16, 0, 0);      \
    } while (0)

    // ---- prologue: chunk0(0),chunk1(0) -> buf0; chunk0(1) -> buf1 ----
    STAGE_A(0, 0, 0, 0); STAGE_A(0, 0, 1, 0);
    STAGE_B(0, 0, 0, 0); STAGE_B(0, 0, 1, 0);
    STAGE_A(0, 1, 0, 0); STAGE_A(0, 1, 1, 0);
    STAGE_B(0, 1, 0, 0); STAGE_B(0, 1, 1, 0);
    STAGE_A(1, 0, 0, 1); STAGE_A(1, 0, 1, 1);
    STAGE_B(1, 0, 0, 1); STAGE_B(1, 0, 1, 1);
    asm volatile("s_waitcnt vmcnt(8)" ::: "memory");   // chunk0(0) ready
    __builtin_amdgcn_s_barrier();
    __builtin_amdgcn_sched_barrier(0);

    for (int kt = 0; kt < NT; ++kt) {
        const int P = kt & 1;
        const int Q = P ^ 1;
        const unsigned ab = P * 32768u;
        const unsigned bb = ab + 16384u;
#pragma unroll
        for (int c = 0; c < 2; ++c) {
            bf16x8 aq[8], bq[4];
#pragma unroll
            for (int n = 0; n < 4; ++n) {
                int r = wn * 64 + n * 16 + lrow;
                bq[n] = *(const bf16x8*)&sh[bb + c * 8192 + r * 32 + 8 * (kg ^ ((r >> 1) & 3))];
            }
#pragma unroll
            for (int i = 0; i < 8; ++i) {
                int r = wm * 128 + i * 16 + lrow;
                aq[i] = *(const bf16x8*)&sh[ab + c * 8192 + r * 32 + 8 * (kg ^ ((r >> 1) & 3))];
            }
            if (c == 0) {
                if (kt + 1 < NT) {
                    STAGE_A(kt + 1, 1, 0, Q); STAGE_A(kt + 1, 1, 1, Q);
                    STAGE_B(kt + 1, 1, 0, Q); STAGE_B(kt + 1, 1, 1, Q);
                }
            } else {
                if (kt + 2 < NT) {
                    STAGE_A(kt + 2, 0, 0, P); STAGE_A(kt + 2, 0, 1, P);
                    STAGE_B(kt + 2, 0, 0, P); STAGE_B(kt + 2, 0, 1, P);
                }
            }
            __builtin_amdgcn_s_setprio(1);
#pragma unroll
            for (int i = 0; i < 8; ++i)
#pragma unroll
                for (int n = 0; n < 4; ++n)
                    acc[i][n] = __builtin_amdgcn_mfma_f32_16x16x32_bf16(
                        aq[i], bq[n], acc[i][n], 0, 0, 0);
            __builtin_amdgcn_s_setprio(0);
            if (c == 0) {   // publish chunk1(kt) for this tile's c1
                if (kt + 1 < NT) asm volatile("s_waitcnt vmcnt(8)" ::: "memory");
                else             asm volatile("s_waitcnt vmcnt(0)" ::: "memory");
            } else {        // publish chunk0(kt+1) for next tile's c0
                if (kt + 2 < NT)      asm volatile("s_waitcnt vmcnt(8)" ::: "memory");
                else if (kt + 1 < NT) asm volatile("s_waitcnt vmcnt(4)" ::: "memory");
                else                  asm volatile("s_waitcnt vmcnt(0)" ::: "memory");
            }
            __builtin_amdgcn_s_barrier();
            __builtin_amdgcn_sched_barrier(0);
        }
    }

    // ---- epilogue: C/D layout col = lane&15, row = (lane>>4)*4 + reg ----
#pragma unroll
    for (int m = 0; m < 8; ++m)
#pragma unroll
        for (int n = 0; n < 4; ++n)
#pragma unroll
            for (int r = 0; r < 4; ++r) {
                int row = tm0 + wm * 128 + m * 16 + kg * 4 + r;
                int col = tn0 + wn * 64 + n * 16 + lrow;
                C[(size_t)row * N_DIM + col] = acc[m][n][r];
            }
#undef STAGE_A
#undef STAGE_B
}

extern "C" void kernel_launch(void* const* d_in, const int* in_sizes, int n_in,
                              void* d_out, int out_size, void* d_ws, size_t ws_size,
                              hipStream_t stream) {
    const float* x = (const float*)d_in[0];
    const float* w = (const float*)d_in[1];
    // d_in[2] (mask) unused: forward value is exactly the ternarized weight.
    float* out = (float*)d_out;

    ushort* xb = (ushort*)d_ws;                       // 64 MB
    ushort* wb = xb + (size_t)M_DIM * K_DIM;          // 128 MB

    {
        int n8 = M_DIM * K_DIM / 8;
        cvt_x_bf16<<<n8 / 256, 256, 0, stream>>>(x, xb);
    }
    {
        int n8 = N_DIM * K_DIM / 8;
        ternarize_w<<<n8 / 256, 256, 0, stream>>>(w, wb);
    }
    {
        dim3 grid((M_DIM / 256) * (N_DIM / 256));     // 32*64 = 2048 blocks
        gemm_bt<<<grid, dim3(512), 0, stream>>>(xb, wb, out);
    }
}

// Round 5
// 1003.208 us; speedup vs baseline: 1.3914x; 1.1130x over previous
//
#include <hip/hip_runtime.h>
#include <hip/hip_bf16.h>

// C[b][o] = sum_i x[b][i] * ternary(w[o][i]);  ternary = sign(w)*(|w|>=0.33)
// M=8192, K=4096, N=16384. Output f32 row-major [M][N].
#define M_DIM 8192
#define K_DIM 4096
#define N_DIM 16384
#define BK 64
#define NT (K_DIM / BK)   // 64 k-tiles
#define NJ (NT / 2)       // 32 double-tile iterations

typedef __attribute__((ext_vector_type(8))) short bf16x8;
typedef __attribute__((ext_vector_type(4))) float f32x4;
typedef __attribute__((address_space(1))) const void glb_cv;
typedef __attribute__((address_space(3))) void lds_v;

// ---------- prepass 1: x f32 -> bf16 (RNE), 8 elems/thread ----------
__global__ void cvt_x_bf16(const float* __restrict__ x, ushort* __restrict__ xb) {
    long i = (long)blockIdx.x * blockDim.x + threadIdx.x;
    const float4* src = reinterpret_cast<const float4*>(x) + i * 2;
    float4 a = src[0], b = src[1];
    float v[8] = {a.x, a.y, a.z, a.w, b.x, b.y, b.z, b.w};
    unsigned r[8];
#pragma unroll
    for (int j = 0; j < 8; ++j) {
        unsigned u = __float_as_uint(v[j]);
        r[j] = (u + 0x7fffu + ((u >> 16) & 1u)) >> 16;
    }
    uint4 o;
    o.x = r[0] | (r[1] << 16);
    o.y = r[2] | (r[3] << 16);
    o.z = r[4] | (r[5] << 16);
    o.w = r[6] | (r[7] << 16);
    reinterpret_cast<uint4*>(xb)[i] = o;
}

// ---------- prepass 2: w f32 -> ternary bf16 {-1,0,+1}, 8 elems/thread ----------
__global__ void ternarize_w(const float* __restrict__ w, ushort* __restrict__ wb) {
    long i = (long)blockIdx.x * blockDim.x + threadIdx.x;
    const float4* src = reinterpret_cast<const float4*>(w) + i * 2;
    float4 a = src[0], b = src[1];
    float v[8] = {a.x, a.y, a.z, a.w, b.x, b.y, b.z, b.w};
    unsigned r[8];
#pragma unroll
    for (int j = 0; j < 8; ++j) {
        unsigned u = __float_as_uint(v[j]);
        r[j] = (fabsf(v[j]) >= 0.33f) ? (0x3F80u | ((u >> 16) & 0x8000u)) : 0u;
    }
    uint4 o;
    o.x = r[0] | (r[1] << 16);
    o.y = r[2] | (r[3] << 16);
    o.z = r[4] | (r[5] << 16);
    o.w = r[6] | (r[7] << 16);
    reinterpret_cast<uint4*>(wb)[i] = o;
}

// ---------- GEMM: 256x256 tile, 8 waves, 8 phases per 2 K-tiles ----------
// LDS (ushort units): [buf2:32768][op2:16384][chunk2:8192][row256:32][slot4:8]
// Swizzle: phys_slot = logical_slot ^ ((row>>1)&3); LDS dest of global_load_lds
// linear, global source inverse-swizzled, ds_read applies the XOR (rule 21).
//
// Iteration j computes K-tiles t0=2j (buf0) and t1=2j+1 (buf1).
// Phase p: tp=p>>2 (buf), c=(p>>1)&1 (k-chunk), mh=p&1 (A row-half).
//   mh==0: read bq[4] + aq[4] (8 ds_read_b128); mh==1: read aq[4] (bq reused).
//   16 MFMA (quadrant mh x chunk c), setprio(1..0) around the cluster.
// Staging, 2 global_load_lds (8KB units) per phase:
//   ph0/1: buf1.c1 <- t1 (A/B)   ph2/3: buf0.c0 <- t0+2 (A/B)
//   ph4/5: buf0.c1 <- t0+2      ph6/7: buf1.c0 <- t1+2
// Waits: vmcnt(8) at end of ph1/3/5/7 — retires exactly the 4-load group
// issued 6 phases earlier, just before its first reader; 8 loads always in
// flight. Last iteration (no ph2-7 staging): waits 8/4/0/0.
// Liveness verified: every staged chunk's previous readers completed a
// closing barrier before the stage issues; every read follows the wait+barrier
// that retired its staging.
__global__ __launch_bounds__(512, 2) void gemm_bt(const ushort* __restrict__ A,
                                                  const ushort* __restrict__ Bm,
                                                  float* __restrict__ C) {
    __shared__ ushort sh[65536];   // 128 KB

    // L3-aware supertile remap: xcd = bid&7 owns m-panels [4x,4x+4);
    // within: 8-col n-groups, 4x8 inner sweep. Bijective for grid 2048.
    unsigned bid = blockIdx.x;
    unsigned xcd = bid & 7u;
    unsigned loc = bid >> 3;                 // 0..255
    unsigned ng  = loc >> 5;                 // 0..7
    unsigned idx = loc & 31u;
    const unsigned tm0 = (xcd * 4u + (idx >> 3)) * 256u;   // m-tile 0..31
    const unsigned tn0 = (ng * 8u + (idx & 7u)) * 256u;    // n-tile 0..63

    const int tid  = threadIdx.x;
    const int lane = tid & 63;
    const int wid  = tid >> 6;
    const int wm   = wid >> 2;        // 0..1 -> rows wm*128
    const int wn   = wid & 3;         // 0..3 -> cols wn*64
    const int lrow = lane & 15;
    const int kg   = lane >> 4;

    // staging decomposition: row-in-half, inverse-swizzled slot
    const int srow = tid >> 2;                  // 0..127
    const int sg   = (tid & 3) ^ ((tid >> 3) & 3);
    const int sdst = tid * 8;                   // ushort offset within 8KB unit

    f32x4 acc[8][4] = {};

#define STAGE_A(kt_, c_, h_, P_) do {                                                       \
        const ushort* _s = A + (size_t)(tm0 + (h_)*128 + srow) * K_DIM                      \
                             + (kt_)*BK + (c_)*32 + sg*8;                                   \
        __builtin_amdgcn_global_load_lds((glb_cv*)_s,                                       \
            (lds_v*)&sh[(P_)*32768 + (c_)*8192 + (h_)*4096 + sdst], 16, 0, 0);              \
    } while (0)
#define STAGE_B(kt_, c_, h_, P_) do {                                                       \
        const ushort* _s = Bm + (size_t)(tn0 + (h_)*128 + srow) * K_DIM                     \
                              + (kt_)*BK + (c_)*32 + sg*8;                                  \
        __builtin_amdgcn_global_load_lds((glb_cv*)_s,                                       \
            (lds_v*)&sh[(P_)*32768 + 16384 + (c_)*8192 + (h_)*4096 + sdst], 16, 0, 0);      \
    } while (0)

    // one phase: reads -> stage -> MFMA cluster -> wait -> barrier
#define PHASE(TP, C, MH, STAGES, WAITS) do {                                                \
        const unsigned _ab = (TP) * 32768u + (C) * 8192u;                                   \
        const unsigned _bb = _ab + 16384u;                                                  \
        if ((MH) == 0) {                                                                    \
            _Pragma("unroll")                                                               \
            for (int n = 0; n < 4; ++n) {                                                   \
                int r = wn * 64 + n * 16 + lrow;                                            \
                bq[n] = *(const bf16x8*)&sh[_bb + r * 32 + 8 * (kg ^ ((r >> 1) & 3))];      \
            }                                                                               \
        }                                                                                   \
        bf16x8 aq[4];                                                                       \
        _Pragma("unroll")                                                                   \
        for (int i = 0; i < 4; ++i) {                                                       \
            int r = wm * 128 + (MH) * 64 + i * 16 + lrow;                                   \
            aq[i] = *(const bf16x8*)&sh[_ab + r * 32 + 8 * (kg ^ ((r >> 1) & 3))];          \
        }                                                                                   \
        STAGES;                                                                             \
        __builtin_amdgcn_s_setprio(1);                                                      \
        _Pragma("unroll")                                                                   \
        for (int i = 0; i < 4; ++i)                                                         \
            _Pragma("unroll")                                                               \
            for (int n = 0; n < 4; ++n)                                                     \
                acc[(MH) * 4 + i][n] = __builtin_amdgcn_mfma_f32_16x16x32_bf16(             \
                    aq[i], bq[n], acc[(MH) * 4 + i][n], 0, 0, 0);                           \
        __builtin_amdgcn_s_setprio(0);                                                      \
        WAITS;                                                                              \
        __builtin_amdgcn_s_barrier();                                                       \
        __builtin_amdgcn_sched_barrier(0);                                                  \
    } while (0)

    // ---- prologue: t0 full -> buf0 (8 loads), t1.c0 -> buf1 (4 loads) ----
    STAGE_A(0, 0, 0, 0); STAGE_A(0, 0, 1, 0);
    STAGE_B(0, 0, 0, 0); STAGE_B(0, 0, 1, 0);
    STAGE_A(0, 1, 0, 0); STAGE_A(0, 1, 1, 0);
    STAGE_B(0, 1, 0, 0); STAGE_B(0, 1, 1, 0);
    STAGE_A(1, 0, 0, 1); STAGE_A(1, 0, 1, 1);
    STAGE_B(1, 0, 0, 1); STAGE_B(1, 0, 1, 1);
    asm volatile("s_waitcnt vmcnt(8)" ::: "memory");   // buf0.c0 ready
    __builtin_amdgcn_s_barrier();
    __builtin_amdgcn_sched_barrier(0);

    for (int j = 0; j < NJ; ++j) {
        const int t1 = 2 * j + 1;
        const bool full = (j < NJ - 1);
        bf16x8 bq[4];
        // ph0/ph1: compute buf0.c0; stage buf1.c1 <- t1
        PHASE(0, 0, 0, { STAGE_A(t1, 1, 0, 1); STAGE_A(t1, 1, 1, 1); }, {});
        PHASE(0, 0, 1, { STAGE_B(t1, 1, 0, 1); STAGE_B(t1, 1, 1, 1); },
              { asm volatile("s_waitcnt vmcnt(8)" ::: "memory"); });
        // ph2/ph3: compute buf0.c1; stage buf0.c0 <- t0+2
        PHASE(0, 1, 0, { if (full) { STAGE_A(t1 + 1, 0, 0, 0); STAGE_A(t1 + 1, 0, 1, 0); } }, {});
        PHASE(0, 1, 1, { if (full) { STAGE_B(t1 + 1, 0, 0, 0); STAGE_B(t1 + 1, 0, 1, 0); } },
              { if (full) asm volatile("s_waitcnt vmcnt(8)" ::: "memory");
                else      asm volatile("s_waitcnt vmcnt(4)" ::: "memory"); });
        // ph4/ph5: compute buf1.c0; stage buf0.c1 <- t0+2
        PHASE(1, 0, 0, { if (full) { STAGE_A(t1 + 1, 1, 0, 0); STAGE_A(t1 + 1, 1, 1, 0); } }, {});
        PHASE(1, 0, 1, { if (full) { STAGE_B(t1 + 1, 1, 0, 0); STAGE_B(t1 + 1, 1, 1, 0); } },
              { if (full) asm volatile("s_waitcnt vmcnt(8)" ::: "memory");
                else      asm volatile("s_waitcnt vmcnt(0)" ::: "memory"); });
        // ph6/ph7: compute buf1.c1; stage buf1.c0 <- t1+2
        PHASE(1, 1, 0, { if (full) { STAGE_A(t1 + 2, 0, 0, 1); STAGE_A(t1 + 2, 0, 1, 1); } }, {});
        PHASE(1, 1, 1, { if (full) { STAGE_B(t1 + 2, 0, 0, 1); STAGE_B(t1 + 2, 0, 1, 1); } },
              { if (full) asm volatile("s_waitcnt vmcnt(8)" ::: "memory");
                else      asm volatile("s_waitcnt vmcnt(0)" ::: "memory"); });
    }

    // ---- epilogue: C/D layout col = lane&15, row = (lane>>4)*4 + reg ----
#pragma unroll
    for (int m = 0; m < 8; ++m)
#pragma unroll
        for (int n = 0; n < 4; ++n)
#pragma unroll
            for (int r = 0; r < 4; ++r) {
                int row = tm0 + wm * 128 + m * 16 + kg * 4 + r;
                int col = tn0 + wn * 64 + n * 16 + lrow;
                C[(size_t)row * N_DIM + col] = acc[m][n][r];
            }
#undef PHASE
#undef STAGE_A
#undef STAGE_B
}

extern "C" void kernel_launch(void* const* d_in, const int* in_sizes, int n_in,
                              void* d_out, int out_size, void* d_ws, size_t ws_size,
                              hipStream_t stream) {
    const float* x = (const float*)d_in[0];
    const float* w = (const float*)d_in[1];
    // d_in[2] (mask) unused: forward value is exactly the ternarized weight.
    float* out = (float*)d_out;

    ushort* xb = (ushort*)d_ws;                       // 64 MB
    ushort* wb = xb + (size_t)M_DIM * K_DIM;          // 128 MB

    {
        int n8 = M_DIM * K_DIM / 8;
        cvt_x_bf16<<<n8 / 256, 256, 0, stream>>>(x, xb);
    }
    {
        int n8 = N_DIM * K_DIM / 8;
        ternarize_w<<<n8 / 256, 256, 0, stream>>>(w, wb);
    }
    {
        dim3 grid((M_DIM / 256) * (N_DIM / 256));     // 32*64 = 2048 blocks
        gemm_bt<<<grid, dim3(512), 0, stream>>>(xb, wb, out);
    }
}